// Round 1
// baseline (257.926 us; speedup 1.0000x reference)
//
#include <hip/hip_runtime.h>
#include <stdint.h>

#define D_MODEL 1024
#define NHEAD 16
#define HEAD_DIM 64
#define SEQ 2048
#define BATCH 2
#define MROWS (BATCH*SEQ)   // 4096

typedef unsigned short u16;
typedef short bf16x8 __attribute__((ext_vector_type(8)));
typedef float f32x4 __attribute__((ext_vector_type(4)));

__device__ inline float bf2f(u16 h){ return __uint_as_float(((unsigned)h)<<16); }
__device__ inline u16 f2bf(float x){
  unsigned u = __float_as_uint(x);
  unsigned r = (u + 0x7FFFu + ((u>>16)&1u)) >> 16;
  return (u16)r;
}

// inline-asm MFMA: avoids builtin operand-type ambiguity; A/B k-mapping
// consistency makes any within-K lane permutation cancel in the dot product.
__device__ inline f32x4 mfma_bf16(bf16x8 a, bf16x8 b, f32x4 c){
  asm("v_mfma_f32_16x16x32_bf16 %0, %1, %2, %0" : "+v"(c) : "v"(a), "v"(b));
  return c;
}

__device__ inline void gld_lds16(const u16* g, u16* l){
  __builtin_amdgcn_global_load_lds(
      (const __attribute__((address_space(1))) void*)g,
      (__attribute__((address_space(3))) void*)l, 16, 0, 0);
}

// ---------------- pack kernels ----------------
__global__ __launch_bounds__(256) void pack_split(const float* __restrict__ src,
                                                  u16* __restrict__ hi, u16* __restrict__ lo, int n4){
  int i = blockIdx.x*256 + threadIdx.x;
  if (i >= n4) return;
  float4 v = ((const float4*)src)[i];
  float vv[4] = {v.x, v.y, v.z, v.w};
  u16 h[4], l[4];
  #pragma unroll
  for (int j=0;j<4;j++){
    h[j] = f2bf(vv[j]);
    l[j] = f2bf(vv[j] - bf2f(h[j]));
  }
  ((ushort4*)hi)[i] = make_ushort4(h[0],h[1],h[2],h[3]);
  ((ushort4*)lo)[i] = make_ushort4(l[0],l[1],l[2],l[3]);
}

__global__ __launch_bounds__(256) void pack_bias(const float* __restrict__ bq, const float* __restrict__ bk,
                                                 const float* __restrict__ bv, float* __restrict__ out){
  int i = blockIdx.x*256 + threadIdx.x;
  if (i < 1024) out[i] = bq[i];
  else if (i < 2048) out[i] = bk[i-1024];
  else if (i < 3072) out[i] = bv[i-2048];
}

// ---------------- GEMM: C = A * B^T (+bias), split-bf16 phases ----------------
// MODE 0: write fp32 out + bias.  MODE 1: bias -> RMSNorm(gain) -> SFN -> q/k/v bf16 [B,H,L,64]
template<int PHASES, int MODE>
__global__ __launch_bounds__(256) void gemm_bt(
    const u16* __restrict__ a_hi, const u16* __restrict__ a_lo,
    const u16* __restrict__ b_hi, const u16* __restrict__ b_lo,
    const float* __restrict__ bias,
    float* __restrict__ out_f,
    u16* __restrict__ qb, u16* __restrict__ kb, u16* __restrict__ vb,
    const float* __restrict__ gq, const float* __restrict__ gk,
    int M, int N, int K)
{
  __shared__ u16 lds[2][8192];   // per buf: A[128][32] then B[128][32]
  const int tid = threadIdx.x;
  const int lane = tid & 63;
  const int w = tid >> 6;
  const int wr = w >> 1, wc = w & 1;
  const int m0 = blockIdx.x * 128;
  const int n0 = blockIdx.y * 128;
  const int KS = K / 32;
  const int NT = PHASES * KS;

  f32x4 acc[4][4];
  #pragma unroll
  for (int i=0;i<4;i++)
    #pragma unroll
    for (int j=0;j<4;j++) acc[i][j] = (f32x4){0.f,0.f,0.f,0.f};

  auto stage = [&](int buf, int kt){
    int ph = (PHASES==1) ? 0 : (kt / KS);
    int kk = (PHASES==1 ? kt : (kt % KS)) * 32;
    const u16* As = (ph==1) ? a_lo : a_hi;
    const u16* Bs = (ph==2) ? b_lo : b_hi;
    u16* base = &lds[buf][0];
    #pragma unroll
    for (int r=0;r<2;r++){
      const u16* g = As + (size_t)(m0 + (tid>>2) + r*64)*K + kk + (tid&3)*8;
      gld_lds16(g, base + w*512 + r*2048);
    }
    #pragma unroll
    for (int r=0;r<2;r++){
      const u16* g = Bs + (size_t)(n0 + (tid>>2) + r*64)*K + kk + (tid&3)*8;
      gld_lds16(g, base + 4096 + w*512 + r*2048);
    }
  };

  auto compute = [&](int buf){
    const u16* la = &lds[buf][0];
    const u16* lb = &lds[buf][4096];
    const int koff = (lane>>4)*8;
    const int rowa = wr*64 + (lane&15);
    const int rowb = wc*64 + (lane&15);
    bf16x8 af[4], bfv[4];
    #pragma unroll
    for (int i=0;i<4;i++) af[i]  = *(const bf16x8*)&la[(rowa + i*16)*32 + koff];
    #pragma unroll
    for (int i=0;i<4;i++) bfv[i] = *(const bf16x8*)&lb[(rowb + i*16)*32 + koff];
    #pragma unroll
    for (int i=0;i<4;i++)
      #pragma unroll
      for (int j=0;j<4;j++)
        acc[i][j] = mfma_bf16(af[i], bfv[j], acc[i][j]);
  };

  stage(0, 0);
  for (int kt=0; kt<NT; ++kt){
    __syncthreads();
    if (kt+1 < NT) stage((kt+1)&1, kt+1);
    compute(kt&1);
  }
  asm volatile("s_nop 7\ns_nop 7");   // MFMA->VALU read hazard guard

  const int gcolbase = n0 + wc*64;
  if (MODE == 0){
    #pragma unroll
    for (int j=0;j<4;j++){
      float bj = bias ? bias[gcolbase + j*16 + (lane&15)] : 0.f;
      #pragma unroll
      for (int i=0;i<4;i++){
        int row = m0 + wr*64 + i*16 + (lane>>4)*4;
        #pragma unroll
        for (int r=0;r<4;r++)
          out_f[(size_t)(row+r)*N + gcolbase + j*16 + (lane&15)] = acc[i][j][r] + bj;
      }
    }
  } else {
    const int sidx = gcolbase >> 6;   // 0..47 head-segment
    const int ttype = sidx < 16 ? 0 : (sidx < 32 ? 1 : 2);
    u16* dst = ttype==0 ? qb : (ttype==1 ? kb : vb);
    const int h = sidx - (ttype==1 ? 16 : (ttype==2 ? 32 : 0));
    float gvals[4], bvals[4];
    #pragma unroll
    for (int j=0;j<4;j++){
      int dh = j*16 + (lane&15);
      bvals[j] = bias[gcolbase + dh];
      gvals[j] = ttype==0 ? gq[dh] : (ttype==1 ? gk[dh] : 1.0f);
    }
    #pragma unroll
    for (int i=0;i<4;i++){
      #pragma unroll
      for (int r=0;r<4;r++){
        float tv[4];
        float ssq = 0.f;
        #pragma unroll
        for (int j=0;j<4;j++){ tv[j] = acc[i][j][r] + bvals[j]; ssq += tv[j]*tv[j]; }
        ssq += __shfl_xor(ssq, 1);
        ssq += __shfl_xor(ssq, 2);
        ssq += __shfl_xor(ssq, 4);
        ssq += __shfl_xor(ssq, 8);
        float s = 1.0f;
        if (ttype < 2) s = 1.0f / sqrtf(ssq * (1.0f/64.0f) + 1e-6f);
        int row = m0 + wr*64 + i*16 + (lane>>4)*4 + r;
        int bi = row >> 11, li = row & 2047;
        size_t obase = ((size_t)(bi*NHEAD + h)*SEQ + li)*HEAD_DIM;
        #pragma unroll
        for (int j=0;j<4;j++){
          float val = tv[j] * s * gvals[j];
          float z = rintf(val * 2.0f);           // round-half-even == jnp.round
          z = fminf(8.0f, fmaxf(-8.0f, z));
          dst[obase + j*16 + (lane&15)] = f2bf(z * 0.5f);   // exact in bf16
        }
      }
    }
  }
}

// ---------------- v [B,H,L,64] -> vT [B,H,64,L] ----------------
__global__ __launch_bounds__(256) void transpose_v(const u16* __restrict__ v, u16* __restrict__ vt){
  __shared__ u16 tl[64][66];
  int bh = blockIdx.x >> 5;
  int l0 = (blockIdx.x & 31) * 64;
  int tid = threadIdx.x;
  #pragma unroll
  for (int it=0; it<2; ++it){
    int idx = tid + it*256;
    int row = idx >> 3, g = idx & 7;
    bf16x8 d = *(const bf16x8*)(v + ((size_t)bh*SEQ + l0 + row)*64 + g*8);
    #pragma unroll
    for (int j=0;j<8;j++) tl[row][g*8+j] = (u16)d[j];
  }
  __syncthreads();
  #pragma unroll
  for (int it=0; it<2; ++it){
    int idx = tid + it*256;
    int dh = idx >> 3, g = idx & 7;
    u16 tmp[8];
    #pragma unroll
    for (int j=0;j<8;j++) tmp[j] = tl[g*8+j][dh];
    *(bf16x8*)(vt + ((size_t)bh*HEAD_DIM + dh)*SEQ + l0 + g*8) = *(const bf16x8*)tmp;
  }
}

// ---------------- flash attention ----------------
__global__ __launch_bounds__(256) void attn_kernel(
    const u16* __restrict__ qb, const u16* __restrict__ kb, const u16* __restrict__ vt,
    u16* __restrict__ attn_out)
{
  __shared__ u16 lds_k[128*64];      // [kv][d], groups-of-8 XOR-swizzled by row&7
  __shared__ u16 lds_v[64*128];      // [dh][kv], swizzled
  __shared__ u16 lds_p[4][32*128];   // per-wave P, swizzled
  const int tid = threadIdx.x, lane = tid & 63, w = tid >> 6;
  const int bh = blockIdx.y;
  const int q0 = blockIdx.x * 128;
  const size_t kvbase = (size_t)bh * SEQ * HEAD_DIM;
  const size_t vtbase = (size_t)bh * HEAD_DIM * SEQ;

  // Q fragments with softmax scale 0.125 folded in (exact: power of 2)
  bf16x8 qf[2][2];
  #pragma unroll
  for (int mf=0; mf<2; mf++)
    #pragma unroll
    for (int ks=0; ks<2; ks++){
      const u16* g = qb + kvbase + (size_t)(q0 + w*32 + mf*16 + (lane&15))*64 + ks*32 + (lane>>4)*8;
      bf16x8 v = *(const bf16x8*)g;
      #pragma unroll
      for (int j=0;j<8;j++) ((u16*)&v)[j] = f2bf(bf2f((u16)v[j]) * 0.125f);
      qf[mf][ks] = v;
    }

  float m_s[2][4], l_s[2][4];
  f32x4 o[2][4];
  #pragma unroll
  for (int mf=0;mf<2;mf++)
    #pragma unroll
    for (int r=0;r<4;r++){ m_s[mf][r] = -3.0e38f; l_s[mf][r] = 0.f; }
  #pragma unroll
  for (int mf=0;mf<2;mf++)
    #pragma unroll
    for (int nv=0;nv<4;nv++) o[mf][nv] = (f32x4){0.f,0.f,0.f,0.f};

  for (int t=0; t<16; ++t){
    const int kv0 = t*128;
    // stage K tile [128][64]
    #pragma unroll
    for (int r=0;r<4;r++){
      int row = (tid>>3) + r*32;
      int grp = tid & 7;
      const u16* g = kb + kvbase + (size_t)(kv0 + row)*64 + ((grp ^ (row&7))<<3);
      gld_lds16(g, &lds_k[w*512 + r*2048]);
    }
    // stage vT tile [64][128]
    #pragma unroll
    for (int r=0;r<4;r++){
      int row = (tid>>4) + r*16;
      int grp = tid & 15;
      const u16* g = vt + vtbase + (size_t)row*SEQ + kv0 + ((grp ^ (row&7))<<3);
      gld_lds16(g, &lds_v[w*512 + r*2048]);
    }
    __syncthreads();

    // S = Q K^T (exact)
    f32x4 s[2][8];
    #pragma unroll
    for (int mf=0;mf<2;mf++)
      #pragma unroll
      for (int nf=0;nf<8;nf++) s[mf][nf] = (f32x4){0.f,0.f,0.f,0.f};
    #pragma unroll
    for (int ks=0; ks<2; ks++){
      #pragma unroll
      for (int nf=0; nf<8; nf++){
        int rowk = nf*16 + (lane&15);
        int grp = (ks*4 + (lane>>4)) ^ (rowk&7);
        bf16x8 kv = *(const bf16x8*)&lds_k[rowk*64 + grp*8];
        s[0][nf] = mfma_bf16(qf[0][ks], kv, s[0][nf]);
        s[1][nf] = mfma_bf16(qf[1][ks], kv, s[1][nf]);
      }
    }
    asm volatile("s_nop 7\ns_nop 7");

    // online softmax
    float csc[2][4];
    #pragma unroll
    for (int mf=0;mf<2;mf++){
      #pragma unroll
      for (int r=0;r<4;r++){
        float vmax = s[mf][0][r];
        #pragma unroll
        for (int nf=1;nf<8;nf++) vmax = fmaxf(vmax, s[mf][nf][r]);
        vmax = fmaxf(vmax, __shfl_xor(vmax,1));
        vmax = fmaxf(vmax, __shfl_xor(vmax,2));
        vmax = fmaxf(vmax, __shfl_xor(vmax,4));
        vmax = fmaxf(vmax, __shfl_xor(vmax,8));
        float mnew = fmaxf(m_s[mf][r], vmax);
        float c = expf(m_s[mf][r] - mnew);
        float rsum = 0.f;
        #pragma unroll
        for (int nf=0;nf<8;nf++){
          float p = expf(s[mf][nf][r] - mnew);
          s[mf][nf][r] = p;
          rsum += p;
        }
        rsum += __shfl_xor(rsum,1);
        rsum += __shfl_xor(rsum,2);
        rsum += __shfl_xor(rsum,4);
        rsum += __shfl_xor(rsum,8);
        l_s[mf][r] = l_s[mf][r]*c + rsum;
        m_s[mf][r] = mnew;
        csc[mf][r] = c;
      }
    }
    #pragma unroll
    for (int mf=0;mf<2;mf++)
      #pragma unroll
      for (int nv=0;nv<4;nv++)
        #pragma unroll
        for (int r=0;r<4;r++) o[mf][nv][r] *= csc[mf][r];

    // P -> per-wave LDS (bf16, swizzled)
    #pragma unroll
    for (int mf=0;mf<2;mf++)
      #pragma unroll
      for (int nf=0;nf<8;nf++)
        #pragma unroll
        for (int r=0;r<4;r++){
          int rowp = mf*16 + (lane>>4)*4 + r;
          int col = nf*16 + (lane&15);
          int slot = (col>>3) ^ (rowp&7);
          lds_p[w][rowp*128 + slot*8 + (col&7)] = f2bf(s[mf][nf][r]);
        }

    // O += P V
    #pragma unroll
    for (int ks=0;ks<4;ks++){
      bf16x8 pa[2];
      #pragma unroll
      for (int mf=0;mf<2;mf++){
        int rowp = mf*16 + (lane&15);
        int grp = (ks*4 + (lane>>4)) ^ (rowp&7);
        pa[mf] = *(const bf16x8*)&lds_p[w][rowp*128 + grp*8];
      }
      #pragma unroll
      for (int nv=0;nv<4;nv++){
        int rowv = nv*16 + (lane&15);
        int grp = (ks*4 + (lane>>4)) ^ (rowv&7);
        bf16x8 vbv = *(const bf16x8*)&lds_v[rowv*128 + grp*8];
        o[0][nv] = mfma_bf16(pa[0], vbv, o[0][nv]);
        o[1][nv] = mfma_bf16(pa[1], vbv, o[1][nv]);
      }
    }
    __syncthreads();
  }
  asm volatile("s_nop 7\ns_nop 7");

  const int b = bh >> 4, h = bh & 15;
  #pragma unroll
  for (int mf=0;mf<2;mf++){
    #pragma unroll
    for (int r=0;r<4;r++){
      float inv = 1.0f / l_s[mf][r];
      int row = q0 + w*32 + mf*16 + (lane>>4)*4 + r;
      size_t obase = ((size_t)b*SEQ + row)*D_MODEL + h*64;
      #pragma unroll
      for (int nv=0;nv<4;nv++)
        attn_out[obase + nv*16 + (lane&15)] = f2bf(o[mf][nv][r] * inv);
    }
  }
}

// ---------------- host ----------------
extern "C" void kernel_launch(void* const* d_in, const int* in_sizes, int n_in,
                              void* d_out, int out_size, void* d_ws, size_t ws_size,
                              hipStream_t stream){
  const float* x  = (const float*)d_in[0];
  const float* wq = (const float*)d_in[1];
  const float* bq = (const float*)d_in[2];
  const float* wk = (const float*)d_in[3];
  const float* bk = (const float*)d_in[4];
  const float* wv = (const float*)d_in[5];
  const float* bv = (const float*)d_in[6];
  const float* wo = (const float*)d_in[7];
  const float* bo = (const float*)d_in[8];
  const float* gq = (const float*)d_in[9];
  const float* gk = (const float*)d_in[10];
  float* out = (float*)d_out;

  char* ws = (char*)d_ws;
  size_t off = 0;
  auto alloc = [&](size_t bytes) -> char* {
    char* p = ws + off; off += (bytes + 255) & ~(size_t)255; return p;
  };
  const size_t ND = (size_t)MROWS * D_MODEL;       // 4M
  u16* x_hi    = (u16*)alloc(ND*2);
  u16* x_lo    = (u16*)alloc(ND*2);
  u16* wqkv_hi = (u16*)alloc((size_t)3072*1024*2);
  u16* wqkv_lo = (u16*)alloc((size_t)3072*1024*2);
  u16* wo_hi   = (u16*)alloc((size_t)1024*1024*2);
  u16* wo_lo   = (u16*)alloc((size_t)1024*1024*2);
  float* bqkv  = (float*)alloc(3072*4);
  u16* q_bf    = (u16*)alloc(ND*2);
  u16* k_bf    = (u16*)alloc(ND*2);
  u16* v_bf    = (u16*)alloc(ND*2);
  u16* vT      = (u16*)alloc(ND*2);
  u16* attn_bf = (u16*)alloc(ND*2);
  (void)ws_size; (void)in_sizes; (void)n_in; (void)out_size;

  pack_split<<<4096, 256, 0, stream>>>(x,  x_hi, x_lo, (int)(ND/4));
  pack_split<<<1024, 256, 0, stream>>>(wq, wqkv_hi,           wqkv_lo,           262144);
  pack_split<<<1024, 256, 0, stream>>>(wk, wqkv_hi + 1048576, wqkv_lo + 1048576, 262144);
  pack_split<<<1024, 256, 0, stream>>>(wv, wqkv_hi + 2097152, wqkv_lo + 2097152, 262144);
  pack_split<<<1024, 256, 0, stream>>>(wo, wo_hi, wo_lo, 262144);
  pack_bias<<<12, 256, 0, stream>>>(bq, bk, bv, bqkv);

  gemm_bt<3,1><<<dim3(32,24), 256, 0, stream>>>(x_hi, x_lo, wqkv_hi, wqkv_lo, bqkv,
        nullptr, q_bf, k_bf, v_bf, gq, gk, MROWS, 3072, 1024);

  transpose_v<<<1024, 256, 0, stream>>>(v_bf, vT);

  attn_kernel<<<dim3(16,32), 256, 0, stream>>>(q_bf, k_bf, vT, attn_bf);

  gemm_bt<1,0><<<dim3(32,8), 256, 0, stream>>>(attn_bf, nullptr, wo_hi, nullptr, bo,
        out, nullptr, nullptr, nullptr, nullptr, nullptr, MROWS, 1024, 1024);
}